// Round 3
// baseline (163.127 us; speedup 1.0000x reference)
//
#include <hip/hip_runtime.h>

// MMD loss: source (4096,256) fp32, target (4096,256) fp32 -> scalar fp32.
// bandwidth closed form: sum(l2) = 2n*S - 2*||m||^2 (relu effect negligible).
// k_prep (256 blocks): fp32->bf16 matrix, row norms sq[], column sums via
//   atomics; last block computes coef = log2(e)/(16*bw).
// k_main (2080 triangular blocks): 128x128 tile, 16x16x32 bf16 MFMA,
//   global_load_lds width=16 with SOURCE-side XOR swizzle (conflict-free LDS
//   reads), double-buffered BK=64 K-loop, epilogue K = t+t^2+t^4+t^8+t^16,
//   t = exp2(-l2*coef) via raw v_exp_f32; last block writes the scalar.

#define NROWS 8192
#define BHALF 4096
#define DDIM  256
#define TILE  128
#define NTILE 64
#define NBLK  2080   // NTILE*(NTILE+1)/2

typedef __attribute__((ext_vector_type(8))) short bf16x8;
typedef __attribute__((ext_vector_type(4))) float f32x4;
typedef __attribute__((ext_vector_type(4))) unsigned short u16x4;

struct Ws {
  double signed_sum;       // -- memset-zeroed region (1048 B) --
  unsigned int ctr1;
  unsigned int ctr2;
  float Ssum;
  float colsum[256];
  float pad;               // -- end zeroed region --
  float coef;
  float sq[NROWS];
};

__device__ __forceinline__ unsigned short f2bf(float x) {
  unsigned int u = __builtin_bit_cast(unsigned int, x);
  return (unsigned short)((u + 0x7fffu + ((u >> 16) & 1u)) >> 16);
}

__device__ __forceinline__ const float* row_ptr(const float* src, const float* tgt, int i) {
  return (i < BHALF) ? (src + (size_t)i * DDIM) : (tgt + (size_t)(i - BHALF) * DDIM);
}

// 256 blocks x 256 threads; 8 rows per wave, ILP shfl trees.
__global__ __launch_bounds__(256) void k_prep(const float* __restrict__ src,
                                              const float* __restrict__ tgt,
                                              Ws* __restrict__ ws,
                                              unsigned short* __restrict__ tb,
                                              int conv) {
  __shared__ float cls[4][256];
  __shared__ float red[4];
  __shared__ int lastFlag;
  int tid = threadIdx.x, wave = tid >> 6, lane = tid & 63;
  int row0 = blockIdx.x * 32 + wave * 8;
  float c0 = 0.f, c1 = 0.f, c2 = 0.f, c3 = 0.f;
  float s[8];
  #pragma unroll
  for (int r = 0; r < 8; ++r) {
    const float4* rp = (const float4*)row_ptr(src, tgt, row0 + r);
    float4 x = rp[lane];
    if (conv) {
      u16x4 b = { f2bf(x.x), f2bf(x.y), f2bf(x.z), f2bf(x.w) };
      *(u16x4*)&tb[(size_t)(row0 + r) * DDIM + lane * 4] = b;
    }
    c0 += x.x; c1 += x.y; c2 += x.z; c3 += x.w;
    s[r] = x.x * x.x + x.y * x.y + x.z * x.z + x.w * x.w;
  }
  #pragma unroll
  for (int off = 32; off > 0; off >>= 1) {
    #pragma unroll
    for (int r = 0; r < 8; ++r) s[r] += __shfl_xor(s[r], off);
  }
  if (lane == 0) {
    float Sw = 0.f;
    #pragma unroll
    for (int r = 0; r < 8; ++r) { ws->sq[row0 + r] = s[r]; Sw += s[r]; }
    atomicAdd(&ws->Ssum, Sw);
  }
  cls[wave][lane * 4 + 0] = c0;
  cls[wave][lane * 4 + 1] = c1;
  cls[wave][lane * 4 + 2] = c2;
  cls[wave][lane * 4 + 3] = c3;
  __syncthreads();
  atomicAdd(&ws->colsum[tid], cls[0][tid] + cls[1][tid] + cls[2][tid] + cls[3][tid]);
  __threadfence();
  __syncthreads();
  if (tid == 0) lastFlag = (atomicAdd(&ws->ctr1, 1u) == 255u) ? 1 : 0;
  __syncthreads();
  if (!lastFlag) return;
  float mc = atomicAdd(&ws->colsum[tid], 0.f);   // coherent read
  float p = mc * mc;
  #pragma unroll
  for (int off = 32; off > 0; off >>= 1) p += __shfl_xor(p, off);
  if (lane == 0) red[wave] = p;
  __syncthreads();
  if (tid == 0) {
    float msq = red[0] + red[1] + red[2] + red[3];
    float S = atomicAdd(&ws->Ssum, 0.f);
    double n = (double)NROWS;
    double sum_l2 = 2.0 * n * (double)S - 2.0 * (double)msq;
    double bw = sum_l2 / (n * n - n) / 4.0;      // / KERNEL_MUL^(KERNEL_NUM/2)
    ws->coef = (float)(1.4426950408889634 / (16.0 * bw)); // log2(e)/(16*bw)
  }
}

__device__ __forceinline__ void stage_tiles(const unsigned short* gA,
                                            const unsigned short* gB,
                                            unsigned short* lA, unsigned short* lB,
                                            int kc) {
  #pragma unroll
  for (int t = 0; t < 4; ++t) {
    __builtin_amdgcn_global_load_lds(
        (const __attribute__((address_space(1))) void*)(gA + (size_t)(t * 8) * DDIM + kc * 64),
        (__attribute__((address_space(3))) void*)(lA + (t * 8) * 64), 16, 0, 0);
    __builtin_amdgcn_global_load_lds(
        (const __attribute__((address_space(1))) void*)(gB + (size_t)(t * 8) * DDIM + kc * 64),
        (__attribute__((address_space(3))) void*)(lB + (t * 8) * 64), 16, 0, 0);
  }
}

// NBLK triangular blocks, 256 thr = 4 waves, 128x128 tile, dbuf BK=64.
template <int FAST>
__global__ __launch_bounds__(256) void k_main(const unsigned short* __restrict__ tb,
                                              const float* __restrict__ src,
                                              const float* __restrict__ tgt,
                                              Ws* __restrict__ ws,
                                              float* __restrict__ out) {
  int idx = blockIdx.x;
  int ti = (int)((129.0 - sqrt(129.0 * 129.0 - 8.0 * (double)idx)) * 0.5);
  while (64 * (ti + 1) - ((ti + 1) * ti) / 2 <= idx) ++ti;
  while (64 * ti - (ti * (ti - 1)) / 2 > idx) --ti;
  int tj = ti + (idx - (64 * ti - (ti * (ti - 1)) / 2));

  __shared__ __align__(16) unsigned short As[2][TILE * 64];
  __shared__ __align__(16) unsigned short Bs[2][TILE * 64];
  __shared__ float wsum[4];

  int tid = threadIdx.x;
  int wave = tid >> 6, lane = tid & 63;
  int wm = wave >> 1, wn = wave & 1;           // 2x2 wave grid, 64x64 each
  int lr = lane & 15, q = lane >> 4;
  int Ib = ti * TILE, Jb = tj * TILE;

  // epilogue sq prefetch (coef-scaled), issued before the K-loop
  float coef = ws->coef;
  float coef2 = 2.f * coef;
  int ibase = Ib + wm * 64;
  int jbase = Jb + wn * 64;
  float scj[4], sci[16];
  #pragma unroll
  for (int n = 0; n < 4; ++n) scj[n] = ws->sq[jbase + n * 16 + lr] * coef;
  #pragma unroll
  for (int m = 0; m < 4; ++m)
    #pragma unroll
    for (int r = 0; r < 4; ++r)
      sci[m * 4 + r] = ws->sq[ibase + m * 16 + q * 4 + r] * coef;

  f32x4 zero = {0.f, 0.f, 0.f, 0.f};
  f32x4 acc[4][4];
  #pragma unroll
  for (int m = 0; m < 4; ++m)
    #pragma unroll
    for (int n = 0; n < 4; ++n) acc[m][n] = zero;

  // FAST staging: per-lane swizzled source, linear LDS dest.
  const unsigned short* gA = nullptr; const unsigned short* gB = nullptr;
  if (FAST) {
    int lrow = lane >> 3;                      // 0..7
    int lchk = (lane & 7) ^ lrow;              // source chunk (swizzle)
    gA = tb + (size_t)(Ib + wave * 32 + lrow) * DDIM + lchk * 8;
    gB = tb + (size_t)(Jb + wave * 32 + lrow) * DDIM + lchk * 8;
  }
  int r0 = tid >> 4, c4 = tid & 15;            // slow-path coords

  if (FAST) stage_tiles(gA, gB, &As[0][(wave * 32) * 64], &Bs[0][(wave * 32) * 64], 0);
  else {
    #pragma unroll
    for (int rr = 0; rr < 8; ++rr) {
      int row = rr * 16 + r0;
      int sw = ((c4 >> 1) ^ (row & 7)) * 8 + (c4 & 1) * 4;
      float4 va = ((const float4*)row_ptr(src, tgt, Ib + row))[c4];
      u16x4 ba = { f2bf(va.x), f2bf(va.y), f2bf(va.z), f2bf(va.w) };
      *(u16x4*)&As[0][row * 64 + sw] = ba;
      float4 vb = ((const float4*)row_ptr(src, tgt, Jb + row))[c4];
      u16x4 bb = { f2bf(vb.x), f2bf(vb.y), f2bf(vb.z), f2bf(vb.w) };
      *(u16x4*)&Bs[0][row * 64 + sw] = bb;
    }
  }

  #pragma unroll
  for (int kc = 0; kc < 4; ++kc) {
    __syncthreads();                           // staged tile for kc is ready
    int nxt = (kc + 1) & 1;
    if (kc < 3) {                              // prefetch next chunk
      if (FAST) stage_tiles(gA, gB, &As[nxt][(wave * 32) * 64], &Bs[nxt][(wave * 32) * 64], kc + 1);
      else {
        #pragma unroll
        for (int rr = 0; rr < 8; ++rr) {
          int row = rr * 16 + r0;
          int sw = ((c4 >> 1) ^ (row & 7)) * 8 + (c4 & 1) * 4;
          float4 va = ((const float4*)row_ptr(src, tgt, Ib + row))[(kc + 1) * 16 + c4];
          u16x4 ba = { f2bf(va.x), f2bf(va.y), f2bf(va.z), f2bf(va.w) };
          *(u16x4*)&As[nxt][row * 64 + sw] = ba;
          float4 vb = ((const float4*)row_ptr(src, tgt, Jb + row))[(kc + 1) * 16 + c4];
          u16x4 bb = { f2bf(vb.x), f2bf(vb.y), f2bf(vb.z), f2bf(vb.w) };
          *(u16x4*)&Bs[nxt][row * 64 + sw] = bb;
        }
      }
    }
    int cur = kc & 1;
    const unsigned short* lA = &As[cur][0];
    const unsigned short* lB = &Bs[cur][0];
    #pragma unroll
    for (int kk = 0; kk < 2; ++kk) {
      int cidx = ((kk * 4 + q) ^ (lr & 7)) << 3;   // swizzled chunk offset (shorts)
      bf16x8 af[4], bfr[4];
      #pragma unroll
      for (int m = 0; m < 4; ++m)
        af[m] = *(const bf16x8*)&lA[(wm * 64 + m * 16 + lr) * 64 + cidx];
      #pragma unroll
      for (int n = 0; n < 4; ++n)
        bfr[n] = *(const bf16x8*)&lB[(wn * 64 + n * 16 + lr) * 64 + cidx];
      #pragma unroll
      for (int m = 0; m < 4; ++m)
        #pragma unroll
        for (int n = 0; n < 4; ++n)
          acc[m][n] = __builtin_amdgcn_mfma_f32_16x16x32_bf16(af[m], bfr[n], acc[m][n], 0, 0, 0);
    }
  }

  // Epilogue: arg = min(2g*coef - sqi*coef - sqj*coef, 0) = -l2*log2(e)/(16bw)
  float lsum = 0.f;
  #pragma unroll
  for (int m = 0; m < 4; ++m) {
    #pragma unroll
    for (int n = 0; n < 4; ++n) {
      f32x4 g = acc[m][n];
      #pragma unroll
      for (int r = 0; r < 4; ++r) {
        float arg = fminf(coef2 * g[r] - sci[m * 4 + r] - scj[n], 0.f);
        float t  = __builtin_amdgcn_exp2f(arg);
        float t2 = t * t, t4 = t2 * t2, t8 = t4 * t4, t16 = t8 * t8;
        lsum += ((t + t2) + (t4 + t8)) + t16;
      }
    }
  }
  #pragma unroll
  for (int off = 32; off > 0; off >>= 1) lsum += __shfl_xor(lsum, off);
  if (lane == 0) wsum[wave] = lsum;
  __syncthreads();
  if (tid == 0) {
    float tot = wsum[0] + wsum[1] + wsum[2] + wsum[3];
    float sA = (ti < 32) ? 1.f : -1.f;         // B=4096 = 32 tiles of 128
    float sB = (tj < 32) ? 1.f : -1.f;
    float fac = sA * sB * ((ti == tj) ? 1.f : 2.f);
    atomicAdd(&ws->signed_sum, (double)(fac * tot));
    __threadfence();
    unsigned int old = atomicAdd(&ws->ctr2, 1u);
    if (old == (unsigned)(NBLK - 1)) {
      __threadfence();
      double tot_all = atomicAdd(&ws->signed_sum, 0.0);   // coherent read
      out[0] = (float)(tot_all / ((double)BHALF * (double)BHALF));
    }
  }
}

extern "C" void kernel_launch(void* const* d_in, const int* in_sizes, int n_in,
                              void* d_out, int out_size, void* d_ws, size_t ws_size,
                              hipStream_t stream) {
  const float* src = (const float*)d_in[0];
  const float* tgt = (const float*)d_in[1];
  Ws* ws = (Ws*)d_ws;
  float* out = (float*)d_out;

  size_t wsoff = (sizeof(Ws) + 255) & ~(size_t)255;
  size_t need = wsoff + (size_t)NROWS * DDIM * 2;
  bool fast = ws_size >= need;
  unsigned short* tb = fast ? (unsigned short*)((char*)d_ws + wsoff) : nullptr;

  hipMemsetAsync(d_ws, 0, 1056, stream);  // signed_sum, ctrs, Ssum, colsum
  hipLaunchKernelGGL(k_prep, dim3(256), dim3(256), 0, stream, src, tgt, ws, tb,
                     fast ? 1 : 0);
  if (fast)
    hipLaunchKernelGGL((k_main<1>), dim3(NBLK), dim3(256), 0, stream, tb, src, tgt, ws, out);
  else
    hipLaunchKernelGGL((k_main<0>), dim3(NBLK), dim3(256), 0, stream, tb, src, tgt, ws, out);
}

// Round 5
// 121.831 us; speedup vs baseline: 1.3390x; 1.3390x over previous
//
#include <hip/hip_runtime.h>

// MMD loss: source (4096,256) fp32, target (4096,256) fp32 -> scalar fp32.
// bandwidth closed form: sum(l2) = 2n*S - 2*||m||^2 (relu effect negligible).
// NO device fences anywhere — visibility between stages comes from kernel
// dispatch boundaries (4 small launches + GEMM):
//   k_prep (256 blk): fp32->bf16 tb, sq[], colsum/Ssum via fire-and-forget atomics
//   k_bw   (1 blk)  : coef = log2(e)/(16*bw)
//   k_main (2080 blk): 128x128 tile bf16 MFMA GEMM, XOR-swizzled global_load_lds,
//                      dbuf BK=64, epilogue t+t^2+t^4+t^8+t^16, plain part[] store
//   k_final(1 blk)  : double-precision sum of part[] -> out

#define NROWS 8192
#define BHALF 4096
#define DDIM  256
#define TILE  128
#define NTILE 64
#define NBLK  2080   // NTILE*(NTILE+1)/2

typedef __attribute__((ext_vector_type(8))) short bf16x8;
typedef __attribute__((ext_vector_type(4))) float f32x4;
typedef __attribute__((ext_vector_type(4))) unsigned short u16x4;

struct Ws {
  float Ssum;              // -- memset-zeroed region starts here --
  float colsum[256];       // -- end zeroed region (1028 B) --
  float coef;
  float sq[NROWS];
  float part[NBLK];
};

__device__ __forceinline__ unsigned short f2bf(float x) {
  unsigned int u = __builtin_bit_cast(unsigned int, x);
  return (unsigned short)((u + 0x7fffu + ((u >> 16) & 1u)) >> 16);
}

__device__ __forceinline__ const float* row_ptr(const float* src, const float* tgt, int i) {
  return (i < BHALF) ? (src + (size_t)i * DDIM) : (tgt + (size_t)(i - BHALF) * DDIM);
}

// 256 blocks x 256 threads; 8 rows per wave. No fences, no last-block logic.
__global__ __launch_bounds__(256) void k_prep(const float* __restrict__ src,
                                              const float* __restrict__ tgt,
                                              Ws* __restrict__ ws,
                                              unsigned short* __restrict__ tb,
                                              int conv) {
  __shared__ float cls[4][256];
  int tid = threadIdx.x, wave = tid >> 6, lane = tid & 63;
  int row0 = blockIdx.x * 32 + wave * 8;
  float c0 = 0.f, c1 = 0.f, c2 = 0.f, c3 = 0.f;
  float s[8];
  #pragma unroll
  for (int r = 0; r < 8; ++r) {
    const float4* rp = (const float4*)row_ptr(src, tgt, row0 + r);
    float4 x = rp[lane];
    if (conv) {
      u16x4 b = { f2bf(x.x), f2bf(x.y), f2bf(x.z), f2bf(x.w) };
      *(u16x4*)&tb[(size_t)(row0 + r) * DDIM + lane * 4] = b;
    }
    c0 += x.x; c1 += x.y; c2 += x.z; c3 += x.w;
    s[r] = x.x * x.x + x.y * x.y + x.z * x.z + x.w * x.w;
  }
  #pragma unroll
  for (int off = 32; off > 0; off >>= 1) {
    #pragma unroll
    for (int r = 0; r < 8; ++r) s[r] += __shfl_xor(s[r], off);
  }
  if (lane == 0) {
    float Sw = 0.f;
    #pragma unroll
    for (int r = 0; r < 8; ++r) { ws->sq[row0 + r] = s[r]; Sw += s[r]; }
    atomicAdd(&ws->Ssum, Sw);
  }
  cls[wave][lane * 4 + 0] = c0;
  cls[wave][lane * 4 + 1] = c1;
  cls[wave][lane * 4 + 2] = c2;
  cls[wave][lane * 4 + 3] = c3;
  __syncthreads();
  atomicAdd(&ws->colsum[tid], cls[0][tid] + cls[1][tid] + cls[2][tid] + cls[3][tid]);
}

// 1 block x 256 threads: colsum/Ssum -> coef. (dispatch boundary = visibility)
__global__ __launch_bounds__(256) void k_bw(Ws* __restrict__ ws) {
  __shared__ float red[4];
  int tid = threadIdx.x, wave = tid >> 6, lane = tid & 63;
  float mc = ws->colsum[tid];
  float p = mc * mc;
  #pragma unroll
  for (int off = 32; off > 0; off >>= 1) p += __shfl_xor(p, off);
  if (lane == 0) red[wave] = p;
  __syncthreads();
  if (tid == 0) {
    float msq = red[0] + red[1] + red[2] + red[3];
    float S = ws->Ssum;
    double n = (double)NROWS;
    double sum_l2 = 2.0 * n * (double)S - 2.0 * (double)msq;
    double bw = sum_l2 / (n * n - n) / 4.0;      // / KERNEL_MUL^(KERNEL_NUM/2)
    ws->coef = (float)(1.4426950408889634 / (16.0 * bw)); // log2(e)/(16*bw)
  }
}

__device__ __forceinline__ void stage_tiles(const unsigned short* gA,
                                            const unsigned short* gB,
                                            unsigned short* lA, unsigned short* lB,
                                            int kc) {
  #pragma unroll
  for (int t = 0; t < 4; ++t) {
    __builtin_amdgcn_global_load_lds(
        (const __attribute__((address_space(1))) void*)(gA + (size_t)(t * 8) * DDIM + kc * 64),
        (__attribute__((address_space(3))) void*)(lA + (t * 8) * 64), 16, 0, 0);
    __builtin_amdgcn_global_load_lds(
        (const __attribute__((address_space(1))) void*)(gB + (size_t)(t * 8) * DDIM + kc * 64),
        (__attribute__((address_space(3))) void*)(lB + (t * 8) * 64), 16, 0, 0);
  }
}

// NBLK triangular blocks, 256 thr = 4 waves, 128x128 tile, dbuf BK=64.
template <int FAST>
__global__ __launch_bounds__(256) void k_main(const unsigned short* __restrict__ tb,
                                              const float* __restrict__ src,
                                              const float* __restrict__ tgt,
                                              Ws* __restrict__ ws) {
  int idx = blockIdx.x;
  int ti = (int)((129.0 - sqrt(129.0 * 129.0 - 8.0 * (double)idx)) * 0.5);
  while (64 * (ti + 1) - ((ti + 1) * ti) / 2 <= idx) ++ti;
  while (64 * ti - (ti * (ti - 1)) / 2 > idx) --ti;
  int tj = ti + (idx - (64 * ti - (ti * (ti - 1)) / 2));

  __shared__ __align__(16) unsigned short As[2][TILE * 64];
  __shared__ __align__(16) unsigned short Bs[2][TILE * 64];
  __shared__ float wsum[4];

  int tid = threadIdx.x;
  int wave = tid >> 6, lane = tid & 63;
  int wm = wave >> 1, wn = wave & 1;           // 2x2 wave grid, 64x64 each
  int lr = lane & 15, q = lane >> 4;
  int Ib = ti * TILE, Jb = tj * TILE;

  // epilogue sq prefetch (coef-scaled), issued before the K-loop
  float coef = ws->coef;
  float coef2 = 2.f * coef;
  int ibase = Ib + wm * 64;
  int jbase = Jb + wn * 64;
  float scj[4], sci[16];
  #pragma unroll
  for (int n = 0; n < 4; ++n) scj[n] = ws->sq[jbase + n * 16 + lr] * coef;
  #pragma unroll
  for (int m = 0; m < 4; ++m)
    #pragma unroll
    for (int r = 0; r < 4; ++r)
      sci[m * 4 + r] = ws->sq[ibase + m * 16 + q * 4 + r] * coef;

  f32x4 zero = {0.f, 0.f, 0.f, 0.f};
  f32x4 acc[4][4];
  #pragma unroll
  for (int m = 0; m < 4; ++m)
    #pragma unroll
    for (int n = 0; n < 4; ++n) acc[m][n] = zero;

  // FAST staging: per-lane XOR-swizzled source, linear LDS dest.
  const unsigned short* gA = nullptr; const unsigned short* gB = nullptr;
  if (FAST) {
    int lrow = lane >> 3;                      // 0..7
    int lchk = (lane & 7) ^ lrow;              // source chunk (swizzle)
    gA = tb + (size_t)(Ib + wave * 32 + lrow) * DDIM + lchk * 8;
    gB = tb + (size_t)(Jb + wave * 32 + lrow) * DDIM + lchk * 8;
  }
  int r0 = tid >> 4, c4 = tid & 15;            // slow-path coords

  if (FAST) stage_tiles(gA, gB, &As[0][(wave * 32) * 64], &Bs[0][(wave * 32) * 64], 0);
  else {
    #pragma unroll
    for (int rr = 0; rr < 8; ++rr) {
      int row = rr * 16 + r0;
      int sw = ((c4 >> 1) ^ (row & 7)) * 8 + (c4 & 1) * 4;
      float4 va = ((const float4*)row_ptr(src, tgt, Ib + row))[c4];
      u16x4 ba = { f2bf(va.x), f2bf(va.y), f2bf(va.z), f2bf(va.w) };
      *(u16x4*)&As[0][row * 64 + sw] = ba;
      float4 vb = ((const float4*)row_ptr(src, tgt, Jb + row))[c4];
      u16x4 bb = { f2bf(vb.x), f2bf(vb.y), f2bf(vb.z), f2bf(vb.w) };
      *(u16x4*)&Bs[0][row * 64 + sw] = bb;
    }
  }

  #pragma unroll
  for (int kc = 0; kc < 4; ++kc) {
    __syncthreads();                           // staged tile for kc is ready
    int nxt = (kc + 1) & 1;
    if (kc < 3) {                              // prefetch next chunk
      if (FAST) stage_tiles(gA, gB, &As[nxt][(wave * 32) * 64], &Bs[nxt][(wave * 32) * 64], kc + 1);
      else {
        #pragma unroll
        for (int rr = 0; rr < 8; ++rr) {
          int row = rr * 16 + r0;
          int sw = ((c4 >> 1) ^ (row & 7)) * 8 + (c4 & 1) * 4;
          float4 va = ((const float4*)row_ptr(src, tgt, Ib + row))[(kc + 1) * 16 + c4];
          u16x4 ba = { f2bf(va.x), f2bf(va.y), f2bf(va.z), f2bf(va.w) };
          *(u16x4*)&As[nxt][row * 64 + sw] = ba;
          float4 vb = ((const float4*)row_ptr(src, tgt, Jb + row))[(kc + 1) * 16 + c4];
          u16x4 bb = { f2bf(vb.x), f2bf(vb.y), f2bf(vb.z), f2bf(vb.w) };
          *(u16x4*)&Bs[nxt][row * 64 + sw] = bb;
        }
      }
    }
    int cur = kc & 1;
    const unsigned short* lA = &As[cur][0];
    const unsigned short* lB = &Bs[cur][0];
    #pragma unroll
    for (int kk = 0; kk < 2; ++kk) {
      int cidx = ((kk * 4 + q) ^ (lr & 7)) << 3;   // swizzled chunk offset (shorts)
      bf16x8 af[4], bfr[4];
      #pragma unroll
      for (int m = 0; m < 4; ++m)
        af[m] = *(const bf16x8*)&lA[(wm * 64 + m * 16 + lr) * 64 + cidx];
      #pragma unroll
      for (int n = 0; n < 4; ++n)
        bfr[n] = *(const bf16x8*)&lB[(wn * 64 + n * 16 + lr) * 64 + cidx];
      #pragma unroll
      for (int m = 0; m < 4; ++m)
        #pragma unroll
        for (int n = 0; n < 4; ++n)
          acc[m][n] = __builtin_amdgcn_mfma_f32_16x16x32_bf16(af[m], bfr[n], acc[m][n], 0, 0, 0);
    }
  }

  // Epilogue: arg = min(2g*coef - sqi*coef - sqj*coef, 0) = -l2*log2(e)/(16bw)
  float lsum = 0.f;
  #pragma unroll
  for (int m = 0; m < 4; ++m) {
    #pragma unroll
    for (int n = 0; n < 4; ++n) {
      f32x4 g = acc[m][n];
      #pragma unroll
      for (int r = 0; r < 4; ++r) {
        float arg = fminf(coef2 * g[r] - sci[m * 4 + r] - scj[n], 0.f);
        float t  = __builtin_amdgcn_exp2f(arg);
        float t2 = t * t, t4 = t2 * t2, t8 = t4 * t4, t16 = t8 * t8;
        lsum += ((t + t2) + (t4 + t8)) + t16;
      }
    }
  }
  #pragma unroll
  for (int off = 32; off > 0; off >>= 1) lsum += __shfl_xor(lsum, off);
  if (lane == 0) wsum[wave] = lsum;
  __syncthreads();
  if (tid == 0) {
    float tot = wsum[0] + wsum[1] + wsum[2] + wsum[3];
    float sA = (ti < 32) ? 1.f : -1.f;         // B=4096 = 32 tiles of 128
    float sB = (tj < 32) ? 1.f : -1.f;
    float fac = sA * sB * ((ti == tj) ? 1.f : 2.f);
    ws->part[blockIdx.x] = fac * tot;          // plain store — NO fence/atomic
  }
}

// 1 block x 256 threads: double-precision reduce of part[] -> out scalar.
__global__ __launch_bounds__(256) void k_final(const Ws* __restrict__ ws,
                                               float* __restrict__ out) {
  __shared__ double red[4];
  int tid = threadIdx.x, wave = tid >> 6, lane = tid & 63;
  double s = 0.0;
  for (int i = tid; i < NBLK; i += 256) s += (double)ws->part[i];
  #pragma unroll
  for (int off = 32; off > 0; off >>= 1) s += __shfl_xor(s, off);
  if (lane == 0) red[wave] = s;
  __syncthreads();
  if (tid == 0)
    out[0] = (float)((red[0] + red[1] + red[2] + red[3]) /
                     ((double)BHALF * (double)BHALF));
}

extern "C" void kernel_launch(void* const* d_in, const int* in_sizes, int n_in,
                              void* d_out, int out_size, void* d_ws, size_t ws_size,
                              hipStream_t stream) {
  const float* src = (const float*)d_in[0];
  const float* tgt = (const float*)d_in[1];
  Ws* ws = (Ws*)d_ws;
  float* out = (float*)d_out;

  size_t wsoff = (sizeof(Ws) + 255) & ~(size_t)255;
  size_t need = wsoff + (size_t)NROWS * DDIM * 2;
  bool fast = ws_size >= need;
  unsigned short* tb = fast ? (unsigned short*)((char*)d_ws + wsoff) : nullptr;

  hipMemsetAsync(d_ws, 0, 1056, stream);  // Ssum + colsum
  hipLaunchKernelGGL(k_prep, dim3(256), dim3(256), 0, stream, src, tgt, ws, tb,
                     fast ? 1 : 0);
  hipLaunchKernelGGL(k_bw, dim3(1), dim3(256), 0, stream, ws);
  if (fast)
    hipLaunchKernelGGL((k_main<1>), dim3(NBLK), dim3(256), 0, stream, tb, src, tgt, ws);
  else
    hipLaunchKernelGGL((k_main<0>), dim3(NBLK), dim3(256), 0, stream, tb, src, tgt, ws);
  hipLaunchKernelGGL(k_final, dim3(1), dim3(256), 0, stream, ws, out);
}

// Round 6
// 107.333 us; speedup vs baseline: 1.5198x; 1.1351x over previous
//
#include <hip/hip_runtime.h>

// MMD loss: source (4096,256) fp32, target (4096,256) fp32 -> scalar fp32.
// bandwidth closed form: sum(l2) = 2n*S - 2*||m||^2 (relu effect negligible).
// NO fences, NO memset: visibility via kernel dispatch boundaries.
//   k_prep (256 blk): fp32->bf16 tb, sq[], per-block partials Spart/cpart
//   k_bw   (1 blk)  : reduce partials -> coef = log2(e)/(16*bw)
//   k_main (2080 blk): 128x128 tile bf16 MFMA GEMM, XOR-swizzled
//                      global_load_lds, SINGLE-buffer BK=64 (33 KB LDS ->
//                      4 blocks/CU), packed-f32 epilogue t+t^2+t^4+t^8+t^16
//   k_final(1 blk)  : double-precision sum of part[] -> out

#define NROWS 8192
#define BHALF 4096
#define DDIM  256
#define TILE  128
#define NTILE 64
#define NBLK  2080   // NTILE*(NTILE+1)/2

typedef __attribute__((ext_vector_type(8))) short bf16x8;
typedef __attribute__((ext_vector_type(4))) float f32x4;
typedef __attribute__((ext_vector_type(2))) float f32x2;
typedef __attribute__((ext_vector_type(4))) unsigned short u16x4;

struct Ws {
  float coef;
  float Spart[256];
  float cpart[256][256];   // per-block column-sum partials
  float sq[NROWS];
  float part[NBLK];
};

__device__ __forceinline__ unsigned short f2bf(float x) {
  unsigned int u = __builtin_bit_cast(unsigned int, x);
  return (unsigned short)((u + 0x7fffu + ((u >> 16) & 1u)) >> 16);
}

__device__ __forceinline__ const float* row_ptr(const float* src, const float* tgt, int i) {
  return (i < BHALF) ? (src + (size_t)i * DDIM) : (tgt + (size_t)(i - BHALF) * DDIM);
}

// 256 blocks x 256 threads; 8 rows per wave. Partials only — no atomics.
__global__ __launch_bounds__(256) void k_prep(const float* __restrict__ src,
                                              const float* __restrict__ tgt,
                                              Ws* __restrict__ ws,
                                              unsigned short* __restrict__ tb,
                                              int conv) {
  __shared__ float cls[4][256];
  __shared__ float sred[4];
  int tid = threadIdx.x, wave = tid >> 6, lane = tid & 63;
  int row0 = blockIdx.x * 32 + wave * 8;
  float c0 = 0.f, c1 = 0.f, c2 = 0.f, c3 = 0.f;
  float s[8];
  #pragma unroll
  for (int r = 0; r < 8; ++r) {
    const float4* rp = (const float4*)row_ptr(src, tgt, row0 + r);
    float4 x = rp[lane];
    if (conv) {
      u16x4 b = { f2bf(x.x), f2bf(x.y), f2bf(x.z), f2bf(x.w) };
      *(u16x4*)&tb[(size_t)(row0 + r) * DDIM + lane * 4] = b;
    }
    c0 += x.x; c1 += x.y; c2 += x.z; c3 += x.w;
    s[r] = x.x * x.x + x.y * x.y + x.z * x.z + x.w * x.w;
  }
  #pragma unroll
  for (int off = 32; off > 0; off >>= 1) {
    #pragma unroll
    for (int r = 0; r < 8; ++r) s[r] += __shfl_xor(s[r], off);
  }
  if (lane == 0) {
    float Sw = 0.f;
    #pragma unroll
    for (int r = 0; r < 8; ++r) { ws->sq[row0 + r] = s[r]; Sw += s[r]; }
    sred[wave] = Sw;
  }
  cls[wave][lane * 4 + 0] = c0;
  cls[wave][lane * 4 + 1] = c1;
  cls[wave][lane * 4 + 2] = c2;
  cls[wave][lane * 4 + 3] = c3;
  __syncthreads();
  ws->cpart[blockIdx.x][tid] = cls[0][tid] + cls[1][tid] + cls[2][tid] + cls[3][tid];
  if (tid == 0) ws->Spart[blockIdx.x] = sred[0] + sred[1] + sred[2] + sred[3];
}

// 1 block x 256 threads: partials -> coef.
__global__ __launch_bounds__(256) void k_bw(Ws* __restrict__ ws) {
  __shared__ float redm[4], reds[4];
  int tid = threadIdx.x, wave = tid >> 6, lane = tid & 63;
  float mc = 0.f;
  for (int b = 0; b < 256; ++b) mc += ws->cpart[b][tid];
  float p = mc * mc;
  float sp = ws->Spart[tid];
  #pragma unroll
  for (int off = 32; off > 0; off >>= 1) {
    p  += __shfl_xor(p, off);
    sp += __shfl_xor(sp, off);
  }
  if (lane == 0) { redm[wave] = p; reds[wave] = sp; }
  __syncthreads();
  if (tid == 0) {
    float msq = redm[0] + redm[1] + redm[2] + redm[3];
    float S   = reds[0] + reds[1] + reds[2] + reds[3];
    double n = (double)NROWS;
    double sum_l2 = 2.0 * n * (double)S - 2.0 * (double)msq;
    double bw = sum_l2 / (n * n - n) / 4.0;      // / KERNEL_MUL^(KERNEL_NUM/2)
    ws->coef = (float)(1.4426950408889634 / (16.0 * bw)); // log2(e)/(16*bw)
  }
}

__device__ __forceinline__ void stage_tiles(const unsigned short* gA,
                                            const unsigned short* gB,
                                            unsigned short* lA, unsigned short* lB,
                                            int kc) {
  #pragma unroll
  for (int t = 0; t < 4; ++t) {
    __builtin_amdgcn_global_load_lds(
        (const __attribute__((address_space(1))) void*)(gA + (size_t)(t * 8) * DDIM + kc * 64),
        (__attribute__((address_space(3))) void*)(lA + (t * 8) * 64), 16, 0, 0);
    __builtin_amdgcn_global_load_lds(
        (const __attribute__((address_space(1))) void*)(gB + (size_t)(t * 8) * DDIM + kc * 64),
        (__attribute__((address_space(3))) void*)(lB + (t * 8) * 64), 16, 0, 0);
  }
}

// NBLK triangular blocks, 256 thr = 4 waves, 128x128 tile, single-buf BK=64.
template <int FAST>
__global__ __launch_bounds__(256, 4) void k_main(const unsigned short* __restrict__ tb,
                                                 const float* __restrict__ src,
                                                 const float* __restrict__ tgt,
                                                 Ws* __restrict__ ws) {
  int idx = blockIdx.x;
  int ti = (int)((129.0 - sqrt(129.0 * 129.0 - 8.0 * (double)idx)) * 0.5);
  while (64 * (ti + 1) - ((ti + 1) * ti) / 2 <= idx) ++ti;
  while (64 * ti - (ti * (ti - 1)) / 2 > idx) --ti;
  int tj = ti + (idx - (64 * ti - (ti * (ti - 1)) / 2));

  __shared__ __align__(16) unsigned short As[TILE * 64];
  __shared__ __align__(16) unsigned short Bs[TILE * 64];
  __shared__ float wsum[4];

  int tid = threadIdx.x;
  int wave = tid >> 6, lane = tid & 63;
  int wm = wave >> 1, wn = wave & 1;           // 2x2 wave grid, 64x64 each
  int lr = lane & 15, q = lane >> 4;
  int Ib = ti * TILE, Jb = tj * TILE;

  // epilogue prefetch: negative coef-scaled row norms
  float coef = ws->coef;
  float coef2 = 2.f * coef;
  int ibase = Ib + wm * 64;
  int jbase = Jb + wn * 64;
  float nscj[4];
  f32x2 nsci01[4], nsci23[4];
  #pragma unroll
  for (int n = 0; n < 4; ++n) nscj[n] = -ws->sq[jbase + n * 16 + lr] * coef;
  #pragma unroll
  for (int m = 0; m < 4; ++m) {
    nsci01[m] = f32x2{ -ws->sq[ibase + m * 16 + q * 4 + 0] * coef,
                       -ws->sq[ibase + m * 16 + q * 4 + 1] * coef };
    nsci23[m] = f32x2{ -ws->sq[ibase + m * 16 + q * 4 + 2] * coef,
                       -ws->sq[ibase + m * 16 + q * 4 + 3] * coef };
  }

  f32x4 zero = {0.f, 0.f, 0.f, 0.f};
  f32x4 acc[4][4];
  #pragma unroll
  for (int m = 0; m < 4; ++m)
    #pragma unroll
    for (int n = 0; n < 4; ++n) acc[m][n] = zero;

  // FAST staging: per-lane XOR-swizzled source, linear LDS dest.
  const unsigned short* gA = nullptr; const unsigned short* gB = nullptr;
  if (FAST) {
    int lrow = lane >> 3;                      // 0..7
    int lchk = (lane & 7) ^ lrow;              // source chunk (swizzle)
    gA = tb + (size_t)(Ib + wave * 32 + lrow) * DDIM + lchk * 8;
    gB = tb + (size_t)(Jb + wave * 32 + lrow) * DDIM + lchk * 8;
  }
  int r0 = tid >> 4, c4 = tid & 15;            // slow-path coords

  #pragma unroll
  for (int kc = 0; kc < 4; ++kc) {
    if (kc) __syncthreads();                   // prior compute done before overwrite
    if (FAST) {
      stage_tiles(gA, gB, &As[(wave * 32) * 64], &Bs[(wave * 32) * 64], kc);
    } else {
      #pragma unroll
      for (int rr = 0; rr < 8; ++rr) {
        int row = rr * 16 + r0;
        int sw = ((c4 >> 1) ^ (row & 7)) * 8 + (c4 & 1) * 4;
        float4 va = ((const float4*)row_ptr(src, tgt, Ib + row))[kc * 16 + c4];
        u16x4 ba = { f2bf(va.x), f2bf(va.y), f2bf(va.z), f2bf(va.w) };
        *(u16x4*)&As[row * 64 + sw] = ba;
        float4 vb = ((const float4*)row_ptr(src, tgt, Jb + row))[kc * 16 + c4];
        u16x4 bb = { f2bf(vb.x), f2bf(vb.y), f2bf(vb.z), f2bf(vb.w) };
        *(u16x4*)&Bs[row * 64 + sw] = bb;
      }
    }
    __syncthreads();                           // staged tile ready (drains vmcnt)
    #pragma unroll
    for (int kk = 0; kk < 2; ++kk) {
      int cidx = ((kk * 4 + q) ^ (lr & 7)) << 3;   // swizzled chunk offset (shorts)
      bf16x8 af[4], bfr[4];
      #pragma unroll
      for (int m = 0; m < 4; ++m)
        af[m] = *(const bf16x8*)&As[(wm * 64 + m * 16 + lr) * 64 + cidx];
      #pragma unroll
      for (int n = 0; n < 4; ++n)
        bfr[n] = *(const bf16x8*)&Bs[(wn * 64 + n * 16 + lr) * 64 + cidx];
      #pragma unroll
      for (int m = 0; m < 4; ++m)
        #pragma unroll
        for (int n = 0; n < 4; ++n)
          acc[m][n] = __builtin_amdgcn_mfma_f32_16x16x32_bf16(af[m], bfr[n], acc[m][n], 0, 0, 0);
    }
  }

  // Packed epilogue: arg = 2g*coef - (sqi+sqj)*coef; K = t+t^2+t^4+t^8+t^16.
  // No clamp: diagonal arg error <= ~1.4e-3 -> t^16 within 1.6% of 1 (negligible).
  const f32x2 c2v = { coef2, coef2 };
  f32x2 accA = {0.f, 0.f}, accB = {0.f, 0.f};
  f32x2 accC = {0.f, 0.f}, accD = {0.f, 0.f};
  #pragma unroll
  for (int m = 0; m < 4; ++m) {
    #pragma unroll
    for (int n = 0; n < 4; ++n) {
      f32x4 g = acc[m][n];
      f32x2 bj = { nscj[n], nscj[n] };
      f32x2 b01 = nsci01[m] + bj;
      f32x2 b23 = nsci23[m] + bj;
      f32x2 a01 = f32x2{g[0], g[1]} * c2v + b01;
      f32x2 a23 = f32x2{g[2], g[3]} * c2v + b23;
      f32x2 t0, t1;
      t0.x = __builtin_amdgcn_exp2f(a01.x); t0.y = __builtin_amdgcn_exp2f(a01.y);
      t1.x = __builtin_amdgcn_exp2f(a23.x); t1.y = __builtin_amdgcn_exp2f(a23.y);
      f32x2 p0 = t0 * t0, p1 = t1 * t1;
      f32x2 q0 = p0 * p0, q1 = p1 * p1;
      f32x2 r0v = q0 * q0, r1v = q1 * q1;
      accA += t0 + p0;
      accB += q0 + r0v;
      accA = r0v * r0v + accA;                 // + t^16
      accC += t1 + p1;
      accD += q1 + r1v;
      accC = r1v * r1v + accC;
    }
  }
  float lsum = (accA.x + accA.y) + (accB.x + accB.y)
             + (accC.x + accC.y) + (accD.x + accD.y);
  #pragma unroll
  for (int off = 32; off > 0; off >>= 1) lsum += __shfl_xor(lsum, off);
  if (lane == 0) wsum[wave] = lsum;
  __syncthreads();
  if (tid == 0) {
    float tot = wsum[0] + wsum[1] + wsum[2] + wsum[3];
    float sA = (ti < 32) ? 1.f : -1.f;         // B=4096 = 32 tiles of 128
    float sB = (tj < 32) ? 1.f : -1.f;
    float fac = sA * sB * ((ti == tj) ? 1.f : 2.f);
    ws->part[blockIdx.x] = fac * tot;          // plain store — NO fence/atomic
  }
}

// 1 block x 256 threads: double-precision reduce of part[] -> out scalar.
__global__ __launch_bounds__(256) void k_final(const Ws* __restrict__ ws,
                                               float* __restrict__ out) {
  __shared__ double red[4];
  int tid = threadIdx.x, wave = tid >> 6, lane = tid & 63;
  double s = 0.0;
  for (int i = tid; i < NBLK; i += 256) s += (double)ws->part[i];
  #pragma unroll
  for (int off = 32; off > 0; off >>= 1) s += __shfl_xor(s, off);
  if (lane == 0) red[wave] = s;
  __syncthreads();
  if (tid == 0)
    out[0] = (float)((red[0] + red[1] + red[2] + red[3]) /
                     ((double)BHALF * (double)BHALF));
}

extern "C" void kernel_launch(void* const* d_in, const int* in_sizes, int n_in,
                              void* d_out, int out_size, void* d_ws, size_t ws_size,
                              hipStream_t stream) {
  const float* src = (const float*)d_in[0];
  const float* tgt = (const float*)d_in[1];
  Ws* ws = (Ws*)d_ws;
  float* out = (float*)d_out;

  size_t wsoff = (sizeof(Ws) + 255) & ~(size_t)255;
  size_t need = wsoff + (size_t)NROWS * DDIM * 2;
  bool fast = ws_size >= need;
  unsigned short* tb = fast ? (unsigned short*)((char*)d_ws + wsoff) : nullptr;

  hipLaunchKernelGGL(k_prep, dim3(256), dim3(256), 0, stream, src, tgt, ws, tb,
                     fast ? 1 : 0);
  hipLaunchKernelGGL(k_bw, dim3(1), dim3(256), 0, stream, ws);
  if (fast)
    hipLaunchKernelGGL((k_main<1>), dim3(NBLK), dim3(256), 0, stream, tb, src, tgt, ws);
  else
    hipLaunchKernelGGL((k_main<0>), dim3(NBLK), dim3(256), 0, stream, tb, src, tgt, ws);
  hipLaunchKernelGGL(k_final, dim3(1), dim3(256), 0, stream, ws, out);
}